// Round 16
// baseline (611.368 us; speedup 1.0000x reference)
//
#include <hip/hip_runtime.h>
#include <hip/hip_bf16.h>
#include <math.h>

#define DEV __device__ __forceinline__
typedef unsigned short u16;
typedef unsigned int u32;
typedef __attribute__((ext_vector_type(8))) short bf16x8;
typedef __attribute__((ext_vector_type(4))) float f32x4;
typedef __attribute__((ext_vector_type(2))) __bf16 bf16x2;

DEV float gelu_f(float x) { return 0.5f * x * (1.f + erff(x * 0.70710678118654752f)); }
DEV int rfl(int v) { return __builtin_amdgcn_readfirstlane(v); }
DEV float rflf(float v) {
  int i = __builtin_amdgcn_readfirstlane(__float_as_int(v));
  return __int_as_float(i);
}
DEV u16 f2b(float x) { __hip_bfloat16 h = __float2bfloat16(x); return *reinterpret_cast<u16*>(&h); }
DEV float b2f(u16 u) { __hip_bfloat16 h; *reinterpret_cast<u16*>(&h) = u; return __bfloat162float(h); }
DEV u32 pack2(float a, float b) { return (u32)f2b(a) | ((u32)f2b(b) << 16); }

// packed bf16-pair dot with f32 accumulate
DEV float dot2bf(u32 a, u32 b, float c) {
#if __has_builtin(__builtin_amdgcn_fdot2_f32_bf16)
  return __builtin_amdgcn_fdot2_f32_bf16(__builtin_bit_cast(bf16x2, a),
                                         __builtin_bit_cast(bf16x2, b), c, false);
#else
  float r;
  asm("v_dot2_f32_bf16 %0, %1, %2, %3" : "=v"(r) : "v"(a), "v"(b), "v"(c));
  return r;
#endif
}

// ---------------- fused prep: zero counters | weight transpose+bf16 | NE convert ------
__global__ void prep_misc(
    int* __restrict__ zbase, long ztot,
    const float* __restrict__ c1Wl, const float* __restrict__ c1Wr,
    const float* __restrict__ c2Wl, const float* __restrict__ c2Wr,
    const float* __restrict__ nodeW, const float* __restrict__ c3Wl,
    const float* __restrict__ c3Wr, const float* __restrict__ lin1W,
    const float* __restrict__ lin2W, u16* __restrict__ WTS,
    const float* __restrict__ node_embed, u16* __restrict__ NE, long nNE)
{
  long total = ztot + 141312 + nNE;
  long i = (long)blockIdx.x * blockDim.x + threadIdx.x;
  long st = (long)gridDim.x * blockDim.x;
  for (; i < total; i += st) {
    if (i < ztot) {
      zbase[i] = 0;
    } else if (i < ztot + 141312) {
      long idx = i - ztot;
      float v;
      if (idx < 49152) {
        const float* src = (idx < 12288) ? c1Wl : (idx < 24576) ? c1Wr : (idx < 36864) ? c2Wl : c2Wr;
        long loc = idx & 12287;
        long m = loc >> 12;
        int c = (int)((loc >> 6) & 63), k = (int)(loc & 63);
        v = src[m * 4096 + k * 64 + c];
      } else if (idx < 51200) {
        long loc = idx - 49152;
        int c = (int)(loc >> 5), k = (int)(loc & 31);
        v = nodeW[k * 64 + c];
      } else if (idx < 137216) {
        long base = (idx < 79872) ? 51200 : (idx < 108544) ? 79872 : 108544;
        const float* src = (idx < 79872) ? c3Wl : (idx < 108544) ? c3Wr : lin1W;
        long loc = idx - base;
        int c = (int)(loc / 448), k = (int)(loc % 448);
        v = src[k * 64 + c];
      } else {
        long loc = idx - 137216;
        int c = (int)(loc >> 6), k = (int)(loc & 63);
        v = lin2W[k * 64 + c];
      }
      WTS[idx] = f2b(v);
    } else {
      long j = i - ztot - 141312;
      NE[j] = f2b(node_embed[j]);
    }
  }
}

// ---------------- fused histogram over 4 graphs ----------------
__global__ void hist4_k(const int* __restrict__ k1, const int* __restrict__ k2,
                        const int* __restrict__ k3, const int* __restrict__ k4,
                        int E, int Z,
                        int* __restrict__ c1, int* __restrict__ c2,
                        int* __restrict__ c3, int* __restrict__ c4) {
  long total = 3L * E + Z;
  long i = (long)blockIdx.x * blockDim.x + threadIdx.x;
  long st = (long)gridDim.x * blockDim.x;
  for (; i < total; i += st) {
    if (i < E)               atomicAdd(&c1[k1[i]], 1);
    else if (i < 2L * E)     atomicAdd(&c2[k2[i - E]], 1);
    else if (i < 3L * E)     atomicAdd(&c3[k3[i - 2L * E]], 1);
    else                     atomicAdd(&c4[k4[i - 3L * E]], 1);
  }
}

// ---------------- fused multi-block exclusive scan (4 graphs) ----------------
__global__ __launch_bounds__(256) void scan_p1f(
    const int* __restrict__ c1, const int* __restrict__ c2,
    const int* __restrict__ c3, const int* __restrict__ c4,
    int n1, int nS, int nb1, int nbS,
    int* __restrict__ b1, int* __restrict__ b2,
    int* __restrict__ b3, int* __restrict__ b4) {
  int blk = blockIdx.x;
  const int* cnt; int* bsum; int n; int lb;
  if (blk < nb1)                { cnt = c1; bsum = b1; n = n1; lb = blk; }
  else if (blk < nb1 + nbS)     { cnt = c2; bsum = b2; n = nS; lb = blk - nb1; }
  else if (blk < nb1 + 2 * nbS) { cnt = c3; bsum = b3; n = nS; lb = blk - nb1 - nbS; }
  else                          { cnt = c4; bsum = b4; n = nS; lb = blk - nb1 - 2 * nbS; }
  __shared__ int ts[256];
  int base = lb * 1024;
  int s = 0;
  #pragma unroll
  for (int k = 0; k < 4; ++k) {
    int g = base + threadIdx.x * 4 + k;
    if (g < n) s += cnt[g];
  }
  ts[threadIdx.x] = s;
  __syncthreads();
  for (int d = 128; d; d >>= 1) {
    if (threadIdx.x < d) ts[threadIdx.x] += ts[threadIdx.x + d];
    __syncthreads();
  }
  if (threadIdx.x == 0) bsum[lb] = ts[0];
}

__global__ __launch_bounds__(256) void scan_p2f(
    int* __restrict__ b1, int* __restrict__ b2, int* __restrict__ b3, int* __restrict__ b4,
    int nb1, int nbS,
    int* __restrict__ rp1, int* __restrict__ rp2, int* __restrict__ rp3, int* __restrict__ rp4,
    int n1, int nS) {
  int g = blockIdx.x;
  int* bsum = g == 0 ? b1 : g == 1 ? b2 : g == 2 ? b3 : b4;
  int* rp   = g == 0 ? rp1 : g == 1 ? rp2 : g == 2 ? rp3 : rp4;
  int nb    = g == 0 ? nb1 : nbS;
  int n     = g == 0 ? n1 : nS;
  __shared__ int ts[256];
  int tid = threadIdx.x;
  int v = (tid < nb) ? bsum[tid] : 0;
  ts[tid] = v;
  __syncthreads();
  for (int d = 1; d < 256; d <<= 1) {
    int w = (tid >= d) ? ts[tid - d] : 0;
    __syncthreads();
    ts[tid] += w;
    __syncthreads();
  }
  if (tid < nb) bsum[tid] = (tid == 0) ? 0 : ts[tid - 1];
  if (tid == 255) rp[n] = ts[255];
}

__global__ __launch_bounds__(256) void scan_p3f(
    const int* __restrict__ c1, const int* __restrict__ c2,
    const int* __restrict__ c3, const int* __restrict__ c4,
    int n1, int nS, int nb1, int nbS,
    const int* __restrict__ b1, const int* __restrict__ b2,
    const int* __restrict__ b3, const int* __restrict__ b4,
    int* __restrict__ rp1, int* __restrict__ rp2,
    int* __restrict__ rp3, int* __restrict__ rp4,
    int* __restrict__ q1, int* __restrict__ q2,
    int* __restrict__ q3, int* __restrict__ q4) {
  int blk = blockIdx.x;
  const int* cnt; const int* bsum; int* rp; int* cursor; int n; int lb;
  if (blk < nb1)                { cnt = c1; bsum = b1; rp = rp1; cursor = q1; n = n1; lb = blk; }
  else if (blk < nb1 + nbS)     { cnt = c2; bsum = b2; rp = rp2; cursor = q2; n = nS; lb = blk - nb1; }
  else if (blk < nb1 + 2 * nbS) { cnt = c3; bsum = b3; rp = rp3; cursor = q3; n = nS; lb = blk - nb1 - nbS; }
  else                          { cnt = c4; bsum = b4; rp = rp4; cursor = q4; n = nS; lb = blk - nb1 - 2 * nbS; }
  __shared__ int ts[256];
  int base = lb * 1024;
  int tid = threadIdx.x;
  int c[4];
  int s = 0;
  #pragma unroll
  for (int k = 0; k < 4; ++k) {
    int g = base + tid * 4 + k;
    c[k] = (g < n) ? cnt[g] : 0;
    s += c[k];
  }
  ts[tid] = s;
  __syncthreads();
  for (int d = 1; d < 256; d <<= 1) {
    int w = (tid >= d) ? ts[tid - d] : 0;
    __syncthreads();
    ts[tid] += w;
    __syncthreads();
  }
  int run = bsum[lb] + ((tid == 0) ? 0 : ts[tid - 1]);
  #pragma unroll
  for (int k = 0; k < 4; ++k) {
    int g = base + tid * 4 + k;
    if (g < n) {
      rp[g] = run;
      cursor[g] = run;
      run += c[k];
    }
  }
}

// ---------------- partitioned fused scatter: block handles keys in its 1/8 dst range ----
#define NPART 8
__global__ void scat4_k(
    const int* __restrict__ edst, const int* __restrict__ esrc,
    const float* __restrict__ attr,
    const int* __restrict__ se_row, const int* __restrict__ se_col, const float* __restrict__ se_val,
    const int* __restrict__ sn_row, const int* __restrict__ sn_col, const float* __restrict__ sn_val,
    const int* __restrict__ ss_col, const int* __restrict__ ss_row, const float* __restrict__ ss_val,
    int E, int Z, int Nn, int S,
    int* __restrict__ q1, int* __restrict__ q2, int* __restrict__ q3, int* __restrict__ q4,
    int* __restrict__ src1s, u16* __restrict__ atrs,
    int2* __restrict__ cv2, int2* __restrict__ cv3, int2* __restrict__ cv4) {
  const int part = blockIdx.x & (NPART - 1);
  const int nb   = gridDim.x >> 3;
  const int bid  = blockIdx.x >> 3;
  const int nlo = (int)((long)part * Nn / NPART);
  const int nhi = (int)((long)(part + 1) * Nn / NPART);
  const int slo = (int)((long)part * S / NPART);
  const int shi = (int)((long)(part + 1) * S / NPART);
  long total = 3L * E + Z;
  long i = (long)bid * blockDim.x + threadIdx.x;
  long st = (long)nb * blockDim.x;
  for (; i < total; i += st) {
    if (i < E) {
      int key = edst[i];
      if (key < nlo || key >= nhi) continue;
      int p = atomicAdd(&q1[key], 1);
      src1s[p] = esrc[i];
      const float* sr = attr + (size_t)i * 16;
      u32* dr = (u32*)(atrs + (size_t)p * 16);
      #pragma unroll
      for (int k = 0; k < 8; ++k) dr[k] = pack2(sr[2 * k], sr[2 * k + 1]);
    } else if (i < 2L * E) {
      long j = i - E;
      int key = se_row[j];
      if (key < slo || key >= shi) continue;
      int p = atomicAdd(&q2[key], 1);
      cv2[p] = make_int2(se_col[j], __float_as_int(se_val[j]));
    } else if (i < 3L * E) {
      long j = i - 2L * E;
      int key = sn_row[j];
      if (key < slo || key >= shi) continue;
      int p = atomicAdd(&q3[key], 1);
      cv3[p] = make_int2(sn_col[j], __float_as_int(sn_val[j]));
    } else {
      long j = i - 3L * E;
      int key = ss_col[j];
      if (key < slo || key >= shi) continue;
      int p = atomicAdd(&q4[key], 1);
      cv4[p] = make_int2(ss_row[j], __float_as_int(ss_val[j]));
    }
  }
}

// ---------------- compose: WECP = pack_bf16(attr1_W @ We[l]), BEC = attr1_b @ We[l] ------
__global__ __launch_bounds__(256) void compose_we(
    const float* __restrict__ a1W, const float* __restrict__ a1b,
    const float* __restrict__ c1We, const float* __restrict__ c2We,
    u32* __restrict__ WECP, float* __restrict__ BEC)
{
  int l = blockIdx.x;
  const float* We = (l < 3) ? (c1We + l * 4096) : (c2We + (l - 3) * 4096);
  __shared__ float wes[4096];
  __shared__ float wecl[1024];
  int tid = threadIdx.x;
  for (int i = tid; i < 4096; i += 256) wes[i] = We[i];
  __syncthreads();
  for (int i = tid; i < 1024; i += 256) {
    int k = i >> 6, j = i & 63;
    float s = 0.f;
    #pragma unroll 16
    for (int m = 0; m < 64; ++m) s += a1W[k * 64 + m] * wes[m * 64 + j];
    wecl[i] = s;
  }
  if (tid < 64) {
    float s = 0.f;
    for (int m = 0; m < 64; ++m) s += a1b[m] * wes[m * 64 + tid];
    BEC[l * 64 + tid] = s;
  }
  __syncthreads();
  for (int i = tid; i < 512; i += 256) {
    int k = i >> 6, j = i & 63;
    WECP[l * 512 + i] = pack2(wecl[(2 * k) * 64 + j], wecl[(2 * k + 1) * 64 + j]);
  }
}

// ---------------- MFMA GEMM; DUAL: split grid; TRI: third weight set (fp32+gelu out) ----
template <int ACT, bool PAIR, bool XBF, bool OBF, bool DUAL, bool TRI>
__global__ __launch_bounds__(256) void gemm_mfma(
    const void* __restrict__ Xv, int nrows, int K,
    const u16* __restrict__ WT1, const float* __restrict__ b1, void* __restrict__ O1v,
    const u16* __restrict__ WT2, const float* __restrict__ b2, void* __restrict__ O2v,
    const void* __restrict__ Xv2,
    const u16* __restrict__ WT3, const float* __restrict__ b3, void* __restrict__ O3v,
    const u16* __restrict__ WT4, const float* __restrict__ b4, void* __restrict__ O4v,
    const u16* __restrict__ WT5, const float* __restrict__ b5, float* __restrict__ O5v)
{
  __shared__ __align__(16) u16 xs[4096];
  __shared__ __align__(16) u16 ws1[4096];
  __shared__ __align__(16) u16 ws2[PAIR ? 4096 : 8];
  __shared__ __align__(16) u16 ws3[TRI ? 4096 : 8];

  int bid = blockIdx.x;
  const void* X_ = Xv;
  const u16* w1p = WT1; const float* b1p = b1; void* o1p = O1v;
  const u16* w2p = WT2; const float* b2p = b2; void* o2p = O2v;
  if constexpr (DUAL) {
    int half = gridDim.x >> 1;
    if (bid >= half) {
      bid -= half;
      X_ = Xv2;
      w1p = WT3; b1p = b3; o1p = O3v;
      w2p = WT4; b2p = b4; o2p = O4v;
    }
  }

  const int tid = threadIdx.x;
  const int row0 = bid * 64;
  const int wid = tid >> 6, lane = tid & 63;
  const int lrow = lane & 15, lgrp = lane >> 4;
  const int r0 = wid * 16;
  const int sr = tid >> 2;
  const int sq = tid & 3;
  const int ssw = sr & 7;

  f32x4 acc[4];
  f32x4 acc2[PAIR ? 4 : 1];
  f32x4 acc3[TRI ? 4 : 1];
  #pragma unroll
  for (int f = 0; f < 4; ++f) {
    acc[f] = (f32x4)0.f;
    if constexpr (PAIR) acc2[f] = (f32x4)0.f;
    if constexpr (TRI)  acc3[f] = (f32x4)0.f;
  }

  for (int kc = 0; kc < K; kc += 64) {
    __syncthreads();
    {
      int gr = row0 + sr;
      int kb = kc + sq * 16;
      uint4 pa, pb;
      if constexpr (XBF) {
        const u16* X = (const u16*)X_;
        if (gr < nrows && kb + 16 <= K) {
          pa = *(const uint4*)&X[(size_t)gr * K + kb];
          pb = *(const uint4*)&X[(size_t)gr * K + kb + 8];
        } else {
          u32 p[8];
          #pragma unroll
          for (int i = 0; i < 8; ++i) {
            u16 a = (gr < nrows && kb + 2 * i < K)     ? X[(size_t)gr * K + kb + 2 * i]     : (u16)0;
            u16 b = (gr < nrows && kb + 2 * i + 1 < K) ? X[(size_t)gr * K + kb + 2 * i + 1] : (u16)0;
            p[i] = (u32)a | ((u32)b << 16);
          }
          pa = make_uint4(p[0], p[1], p[2], p[3]);
          pb = make_uint4(p[4], p[5], p[6], p[7]);
        }
      } else {
        const float* X = (const float*)X_;
        float f[16];
        if (gr < nrows && kb + 16 <= K) {
          #pragma unroll
          for (int i = 0; i < 4; ++i)
            *(float4*)&f[i * 4] = *(const float4*)&X[(size_t)gr * K + kb + i * 4];
        } else {
          #pragma unroll
          for (int i = 0; i < 16; ++i)
            f[i] = (gr < nrows && kb + i < K) ? X[(size_t)gr * K + kb + i] : 0.f;
        }
        u32 p[8];
        #pragma unroll
        for (int i = 0; i < 8; ++i) p[i] = pack2(f[2 * i], f[2 * i + 1]);
        pa = make_uint4(p[0], p[1], p[2], p[3]);
        pb = make_uint4(p[4], p[5], p[6], p[7]);
      }
      *(uint4*)&xs[sr * 64 + (((sq * 2))     ^ ssw) * 8] = pa;
      *(uint4*)&xs[sr * 64 + (((sq * 2 + 1)) ^ ssw) * 8] = pb;
    }
    {
      int kb = kc + sq * 16;
      uint4 qa, qb;
      #define STAGE_W(WP, WS)                                                       \
        if (kb + 16 <= K) {                                                         \
          qa = *(const uint4*)&WP[(size_t)sr * K + kb];                             \
          qb = *(const uint4*)&WP[(size_t)sr * K + kb + 8];                         \
        } else {                                                                    \
          u32 p[8];                                                                 \
          _Pragma("unroll")                                                         \
          for (int i = 0; i < 8; ++i) {                                             \
            u16 a = (kb + 2 * i < K)     ? WP[(size_t)sr * K + kb + 2 * i]     : (u16)0; \
            u16 b = (kb + 2 * i + 1 < K) ? WP[(size_t)sr * K + kb + 2 * i + 1] : (u16)0; \
            p[i] = (u32)a | ((u32)b << 16);                                         \
          }                                                                         \
          qa = make_uint4(p[0], p[1], p[2], p[3]);                                  \
          qb = make_uint4(p[4], p[5], p[6], p[7]);                                  \
        }                                                                           \
        *(uint4*)&WS[sr * 64 + (((sq * 2))     ^ ssw) * 8] = qa;                    \
        *(uint4*)&WS[sr * 64 + (((sq * 2 + 1)) ^ ssw) * 8] = qb;
      STAGE_W(w1p, ws1)
      if constexpr (PAIR) { STAGE_W(w2p, ws2) }
      if constexpr (TRI)  { STAGE_W(WT5, ws3) }
      #undef STAGE_W
    }
    __syncthreads();
    #pragma unroll
    for (int kh = 0; kh < 2; ++kh) {
      const int g = (4 * kh + lgrp) ^ (lrow & 7);
      bf16x8 a = *(const bf16x8*)&xs[(r0 + lrow) * 64 + g * 8];
      #pragma unroll
      for (int f = 0; f < 4; ++f) {
        int col = f * 16 + lrow;
        bf16x8 b = *(const bf16x8*)&ws1[col * 64 + g * 8];
        acc[f] = __builtin_amdgcn_mfma_f32_16x16x32_bf16(a, b, acc[f], 0, 0, 0);
        if constexpr (PAIR) {
          bf16x8 b2v = *(const bf16x8*)&ws2[col * 64 + g * 8];
          acc2[f] = __builtin_amdgcn_mfma_f32_16x16x32_bf16(a, b2v, acc2[f], 0, 0, 0);
        }
        if constexpr (TRI) {
          bf16x8 b3v = *(const bf16x8*)&ws3[col * 64 + g * 8];
          acc3[f] = __builtin_amdgcn_mfma_f32_16x16x32_bf16(a, b3v, acc3[f], 0, 0, 0);
        }
      }
    }
  }

  #pragma unroll
  for (int f = 0; f < 4; ++f) {
    int col = f * 16 + lrow;
    float bv = b1p[col];
    float bv2 = 0.f, bv3 = 0.f;
    if constexpr (PAIR) bv2 = b2p[col];
    if constexpr (TRI)  bv3 = b5[col];
    #pragma unroll
    for (int r = 0; r < 4; ++r) {
      int grow = row0 + r0 + lgrp * 4 + r;
      if (grow >= nrows) continue;
      float v = acc[f][r] + bv;
      if constexpr (ACT == 1) v = gelu_f(v);
      if constexpr (OBF) ((u16*)o1p)[(size_t)grow * 64 + col] = f2b(v);
      else               ((float*)o1p)[(size_t)grow * 64 + col] = v;
      if constexpr (PAIR) {
        float v2 = acc2[f][r] + bv2;
        if constexpr (ACT == 1) v2 = gelu_f(v2);
        if constexpr (OBF) ((u16*)o2p)[(size_t)grow * 64 + col] = f2b(v2);
        else               ((float*)o2p)[(size_t)grow * 64 + col] = v2;
      }
      if constexpr (TRI) {
        float v3 = gelu_f(acc3[f][r] + bv3);
        O5v[(size_t)grow * 64 + col] = v3;
      }
    }
  }
}

// ---------------- fused dual-conv gather GATv2 (1 dst/wave, 4x edge unroll, dot2 ep) ----
__global__ __launch_bounds__(256) void gat_gather2(
    const int* __restrict__ rowptr,
    const int* __restrict__ srcs, const u16* __restrict__ atrs,
    const u32* __restrict__ wecp1, const float* __restrict__ bec1,
    const float* __restrict__ att1, const float* __restrict__ bias1,
    const u32* __restrict__ wecp2, const float* __restrict__ bec2,
    const float* __restrict__ att2, const float* __restrict__ bias2,
    const u16* __restrict__ xl1, const u16* __restrict__ xr1,
    const u16* __restrict__ pre1, u16* __restrict__ out1,
    const u16* __restrict__ xl2, const u16* __restrict__ xr2,
    const u16* __restrict__ pre2, u16* __restrict__ out2, int n)
{
  int tid = threadIdx.x;
  int wid = tid >> 6, lane = tid & 63;
  int d = blockIdx.x * 4 + wid;
  if (d >= n) return;
  u32 w1p[8], w2p[8];
  #pragma unroll
  for (int k = 0; k < 8; ++k) {
    w1p[k] = wecp1[k * 64 + lane];
    w2p[k] = wecp2[k * 64 + lane];
  }
  float be1 = bec1[lane], be2 = bec2[lane];
  float at1 = att1[lane], at2 = att2[lane];
  float xr1v = b2f(xr1[(size_t)d * 64 + lane]);
  float xr2v = b2f(xr2[(size_t)d * 64 + lane]);
  float n1 = 0.f, d1 = 0.f, n2 = 0.f, d2 = 0.f;
  int j0 = rfl(rowptr[d]), j1 = rfl(rowptr[d + 1]);
  int j = j0;
  // ---- 4-edge unrolled main body ----
  for (; j + 4 <= j1; j += 4) {
    int s0_ = rfl(srcs[j]);
    int s1_ = rfl(srcs[j + 1]);
    int s2_ = rfl(srcs[j + 2]);
    int s3_ = rfl(srcs[j + 3]);
    const u32* ar0 = (const u32*)(atrs + (size_t)j * 16);
    const u32* ar1 = ar0 + 8;
    const u32* ar2 = ar0 + 16;
    const u32* ar3 = ar0 + 24;
    float xa1[4], xa2[4];
    xa1[0] = b2f(xl1[(size_t)s0_ * 64 + lane]);
    xa1[1] = b2f(xl1[(size_t)s1_ * 64 + lane]);
    xa1[2] = b2f(xl1[(size_t)s2_ * 64 + lane]);
    xa1[3] = b2f(xl1[(size_t)s3_ * 64 + lane]);
    xa2[0] = b2f(xl2[(size_t)s0_ * 64 + lane]);
    xa2[1] = b2f(xl2[(size_t)s1_ * 64 + lane]);
    xa2[2] = b2f(xl2[(size_t)s2_ * 64 + lane]);
    xa2[3] = b2f(xl2[(size_t)s3_ * 64 + lane]);
    float e1[4] = {be1, be1, be1, be1};
    float e2[4] = {be2, be2, be2, be2};
    #pragma unroll
    for (int k = 0; k < 8; ++k) {
      u32 p0 = ar0[k], p1 = ar1[k], p2 = ar2[k], p3 = ar3[k];
      e1[0] = dot2bf(p0, w1p[k], e1[0]); e2[0] = dot2bf(p0, w2p[k], e2[0]);
      e1[1] = dot2bf(p1, w1p[k], e1[1]); e2[1] = dot2bf(p1, w2p[k], e2[1]);
      e1[2] = dot2bf(p2, w1p[k], e1[2]); e2[2] = dot2bf(p2, w2p[k], e2[2]);
      e1[3] = dot2bf(p3, w1p[k], e1[3]); e2[3] = dot2bf(p3, w2p[k], e2[3]);
    }
    float t1[4], t2[4];
    #pragma unroll
    for (int q = 0; q < 4; ++q) {
      float m1 = xa1[q] + xr1v + e1[q];
      float m2 = xa2[q] + xr2v + e2[q];
      float l1 = m1 < 0.f ? 0.2f * m1 : m1;
      float l2 = m2 < 0.f ? 0.2f * m2 : m2;
      t1[q] = at1 * l1;
      t2[q] = at2 * l2;
    }
    #pragma unroll
    for (int o = 32; o; o >>= 1) {
      #pragma unroll
      for (int q = 0; q < 4; ++q) {
        t1[q] += __shfl_xor(t1[q], o, 64);
        t2[q] += __shfl_xor(t2[q], o, 64);
      }
    }
    #pragma unroll
    for (int q = 0; q < 4; ++q) {
      float x1 = __expf(t1[q]), x2 = __expf(t2[q]);
      n1 += x1 * xa1[q]; d1 += x1;
      n2 += x2 * xa2[q]; d2 += x2;
    }
  }
  // ---- remainder (0..3 edges) ----
  for (; j < j1; ++j) {
    int s = rfl(srcs[j]);
    const u32* arow = (const u32*)(atrs + (size_t)j * 16);
    float xl1v = b2f(xl1[(size_t)s * 64 + lane]);
    float xl2v = b2f(xl2[(size_t)s * 64 + lane]);
    float ep1 = be1, ep2 = be2;
    #pragma unroll
    for (int k = 0; k < 8; ++k) {
      u32 pk = arow[k];
      ep1 = dot2bf(pk, w1p[k], ep1);
      ep2 = dot2bf(pk, w2p[k], ep2);
    }
    float m1 = xl1v + xr1v + ep1;
    float m2 = xl2v + xr2v + ep2;
    float lr1 = m1 < 0.f ? 0.2f * m1 : m1;
    float lr2 = m2 < 0.f ? 0.2f * m2 : m2;
    float t1 = at1 * lr1, t2 = at2 * lr2;
    #pragma unroll
    for (int o = 32; o; o >>= 1) {
      t1 += __shfl_xor(t1, o, 64);
      t2 += __shfl_xor(t2, o, 64);
    }
    float ex1 = __expf(t1), ex2 = __expf(t2);
    n1 += ex1 * xl1v; d1 += ex1;
    n2 += ex2 * xl2v; d2 += ex2;
  }
  size_t base = (size_t)d * 64 + lane;
  float v1 = n1 / (d1 + 1e-16f) + bias1[lane];
  float v2 = n2 / (d2 + 1e-16f) + bias2[lane];
  out1[base] = f2b(gelu_f(v1) + b2f(pre1[base]));
  out2[base] = f2b(gelu_f(v2) + b2f(pre2[base]));
}

// ---------------- fused gather GATv2 (segment graph, 1 seg/wave, packed cv) ----------
__global__ __launch_bounds__(256) void gat_seg_g(
    const int* __restrict__ rowptr, const int2* __restrict__ cv,
    const float* __restrict__ we3, const float* __restrict__ att,
    const float* __restrict__ bias,
    const u16* __restrict__ xl, const u16* __restrict__ xr,
    float* __restrict__ out, int n)
{
  int tid = threadIdx.x;
  int wid = tid >> 6, lane = tid & 63;
  int d = blockIdx.x * 4 + wid;
  if (d >= n) return;
  float we3v = we3[lane], attv = att[lane], bsv = bias[lane];
  float xrv = b2f(xr[(size_t)d * 64 + lane]);
  float accn = 0.f, accd = 0.f;
  int j0 = rfl(rowptr[d]), j1 = rfl(rowptr[d + 1]);
  for (int j = j0; j < j1; ++j) {
    int2 r = cv[j];
    int s = rfl(r.x);
    float vv = rflf(__int_as_float(r.y));
    float ep = vv * we3v;
    float xlv = b2f(xl[(size_t)s * 64 + lane]);
    float m = xlv + xrv + ep;
    float lr = m < 0.f ? 0.2f * m : m;
    float t = attv * lr;
    #pragma unroll
    for (int o = 32; o; o >>= 1) t += __shfl_xor(t, o, 64);
    float ex = __expf(t);
    accn += ex * xlv;
    accd += ex;
  }
  float v = accn / (accd + 1e-16f) + bsv;
  out[(size_t)d * 64 + lane] = gelu_f(v);
}

// ---------------- fused xf build, role-split, 2x edge unroll for MLP ----------------
__global__ __launch_bounds__(256) void xf_build(
    const int* __restrict__ rp2, const int2* __restrict__ cv2,
    const int* __restrict__ rp3, const int2* __restrict__ cv3,
    const float* __restrict__ edge_embed, const float* __restrict__ attr,
    const float* __restrict__ W2, const float* __restrict__ b2,
    const float* __restrict__ seg_embed, const float* __restrict__ time_embed,
    const float* __restrict__ week_embed,
    const int* __restrict__ cur_t, const int* __restrict__ cur_w,
    const u16* __restrict__ h, const u16* __restrict__ nf,
    float* __restrict__ xf, int S)
{
  __shared__ float ws[1024];
  __shared__ float bs[64];
  int tid = threadIdx.x;
  for (int i = tid; i < 1024; i += 256) ws[i] = W2[i];
  if (tid < 64) bs[tid] = b2[tid];
  __syncthreads();
  int wid = tid >> 6, lane = tid & 63;
  int gw = blockIdx.x * 4 + wid;
  int s = gw >> 1, role = gw & 1;
  if (s >= S) return;
  float* row = xf + (size_t)s * 448;
  if (role == 0) {
    row[lane]       = seg_embed[(size_t)s * 64 + lane];
    row[320 + lane] = time_embed[cur_t[0] * 64 + lane];
    row[384 + lane] = week_embed[cur_w[0] * 64 + lane];
    float acc1 = 0.f, aat = 0.f, vs = 0.f;
    int j0 = rfl(rp2[s]), j1 = rfl(rp2[s + 1]);
    int j = j0;
    for (; j + 2 <= j1; j += 2) {
      int2 ra = cv2[j], rb = cv2[j + 1];
      int ca = rfl(ra.x), cb = rfl(rb.x);
      float va = rflf(__int_as_float(ra.y)), vb = rflf(__int_as_float(rb.y));
      float ea = edge_embed[(size_t)ca * 64 + lane];
      float eb = edge_embed[(size_t)cb * 64 + lane];
      float aa = attr[(size_t)ca * 16 + (lane & 15)];
      float ab = attr[(size_t)cb * 16 + (lane & 15)];
      acc1 += va * ea + vb * eb;
      aat  += va * aa + vb * ab;
      vs   += va + vb;
    }
    for (; j < j1; ++j) {
      int2 r = cv2[j];
      int c = rfl(r.x);
      float v = rflf(__int_as_float(r.y));
      acc1 += v * edge_embed[(size_t)c * 64 + lane];
      aat  += v * attr[(size_t)c * 16 + (lane & 15)];
      vs   += v;
    }
    float x2 = vs * bs[lane];
    #pragma unroll
    for (int k = 0; k < 16; ++k)
      x2 += __shfl(aat, k, 64) * ws[k * 64 + lane];
    row[64 + lane]  = acc1;
    row[128 + lane] = x2;
  } else {
    float acch = 0.f, accf = 0.f;
    int j0 = rfl(rp3[s]), j1 = rfl(rp3[s + 1]);
    int j = j0;
    for (; j + 2 <= j1; j += 2) {
      int2 ra = cv3[j], rb = cv3[j + 1];
      int ca = rfl(ra.x), cb = rfl(rb.x);
      float va = rflf(__int_as_float(ra.y)), vb = rflf(__int_as_float(rb.y));
      float ha = b2f(h[(size_t)ca * 64 + lane]);
      float hb = b2f(h[(size_t)cb * 64 + lane]);
      float fa = b2f(nf[(size_t)ca * 64 + lane]);
      float fb = b2f(nf[(size_t)cb * 64 + lane]);
      acch += va * ha + vb * hb;
      accf += va * fa + vb * fb;
    }
    for (; j < j1; ++j) {
      int2 r = cv3[j];
      int c = rfl(r.x);
      float v = rflf(__int_as_float(r.y));
      acch += v * b2f(h[(size_t)c * 64 + lane]);
      accf += v * b2f(nf[(size_t)c * 64 + lane]);
    }
    row[192 + lane] = acch;
    row[256 + lane] = accf;
  }
}

// ---------------- head ----------------
__global__ __launch_bounds__(256) void head_k(
    const float* __restrict__ y2, const float* __restrict__ xfg,
    const float* __restrict__ outW, const float* __restrict__ outb,
    float* __restrict__ out, int S)
{
  int wid = threadIdx.x >> 6, lane = threadIdx.x & 63;
  int s = blockIdx.x * 4 + wid;
  if (s >= S) return;
  float t = y2[(size_t)s * 64 + lane] * outW[lane] + xfg[(size_t)s * 64 + lane] * outW[64 + lane];
  #pragma unroll
  for (int o = 32; o; o >>= 1) t += __shfl_xor(t, o, 64);
  if (lane == 0) {
    float z = t + outb[0];
    out[s] = 3600.f / (1.f + __expf(-z));
  }
}

extern "C" void kernel_launch(void* const* d_in, const int* in_sizes, int n_in,
                              void* d_out, int out_size, void* d_ws, size_t ws_size,
                              hipStream_t stream)
{
  const float* x_rec       = (const float*)d_in[0];
  const float* attr        = (const float*)d_in[1];
  const float* se_val      = (const float*)d_in[2];
  const float* sn_val      = (const float*)d_in[3];
  const float* ss_val      = (const float*)d_in[4];
  const float* node_embed  = (const float*)d_in[5];
  const float* edge_embed  = (const float*)d_in[6];
  const float* seg_embed   = (const float*)d_in[7];
  const float* time_embed  = (const float*)d_in[8];
  const float* week_embed  = (const float*)d_in[9];
  const float* node_lin_W  = (const float*)d_in[10];
  const float* node_lin_b  = (const float*)d_in[11];
  const float* attr2_W     = (const float*)d_in[14];
  const float* attr2_b     = (const float*)d_in[15];
  const float* c1_Wl       = (const float*)d_in[16];
  const float* c1_bl       = (const float*)d_in[17];
  const float* c1_Wr       = (const float*)d_in[18];
  const float* c1_br       = (const float*)d_in[19];
  const float* c1_att      = (const float*)d_in[21];
  const float* c1_bias     = (const float*)d_in[22];
  const float* c2_Wl       = (const float*)d_in[23];
  const float* c2_bl       = (const float*)d_in[24];
  const float* c2_Wr       = (const float*)d_in[25];
  const float* c2_br       = (const float*)d_in[26];
  const float* c2_att      = (const float*)d_in[28];
  const float* c2_bias     = (const float*)d_in[29];
  const float* c3_Wl       = (const float*)d_in[30];
  const float* c3_bl       = (const float*)d_in[31];
  const float* c3_Wr       = (const float*)d_in[32];
  const float* c3_br       = (const float*)d_in[33];
  const float* c3_We       = (const float*)d_in[34];
  const float* c3_att      = (const float*)d_in[35];
  const float* c3_bias     = (const float*)d_in[36];
  const float* lin1_W      = (const float*)d_in[37];
  const float* lin1_b      = (const float*)d_in[38];
  const float* lin2_W      = (const float*)d_in[39];
  const float* lin2_b      = (const float*)d_in[40];
  const float* out_W       = (const float*)d_in[41];
  const float* out_b       = (const float*)d_in[42];
  const int* edge_index    = (const int*)d_in[43];
  const int* se_row        = (const int*)d_in[44];
  const int* se_col        = (const int*)d_in[45];
  const int* sn_row        = (const int*)d_in[46];
  const int* sn_col        = (const int*)d_in[47];
  const int* ss_row        = (const int*)d_in[48];
  const int* ss_col        = (const int*)d_in[49];
  const int* cur_t         = (const int*)d_in[50];
  const int* cur_w         = (const int*)d_in[51];

  const int N = in_sizes[0] / 32;
  const int E = in_sizes[1] / 16;
  const int S = in_sizes[7] / 64;
  const int NNZSS = in_sizes[4];

  // workspace layout (float units)
  float* W = (float*)d_ws;
  size_t o = 0;
  u16* A   = (u16*)(W + o); o += (size_t)N * 32;
  u16* B   = (u16*)(W + o); o += (size_t)N * 32;
  u16* A2  = (u16*)(W + o); o += (size_t)N * 32;
  u16* B2  = (u16*)(W + o); o += (size_t)N * 32;
  u16* Hc  = (u16*)(W + o); o += (size_t)N * 32;
  u16* F0  = (u16*)(W + o); o += (size_t)N * 32;
  u16* Fc  = (u16*)(W + o); o += (size_t)N * 32;
  u16* NE  = (u16*)(W + o); o += (size_t)N * 32;  // node_embed bf16
  u16* ATRS = (u16*)(W + o); o += (size_t)E * 8;  // CSR-ordered bf16 attr rows
  float* XF  = W + o; o += (size_t)S * 448;
  float* XFG = W + o; o += (size_t)S * 64;
  float* Y   = W + o; o += (size_t)S * 64;
  float* Y2  = W + o; o += (size_t)S * 64;
  u32* WECP  = (u32*)(W + o); o += 6 * 512;       // packed bf16-pair composed We
  float* BEC = W + o; o += 6 * 64;
  u16* WTS   = (u16*)(W + o); o += 70656;
  int2* cv2  = (int2*)(W + o); o += 2L * E;       // packed (col,val) records
  int2* cv3  = (int2*)(W + o); o += 2L * E;
  int2* cv4  = (int2*)(W + o); o += 2L * NNZSS;
  int* I = (int*)(W + o);
  size_t q = 0;
  int* cur1 = I + q; q += N + 1;
  int* cur2 = I + q; q += S + 1;
  int* cur3 = I + q; q += S + 1;
  int* cur4 = I + q; q += S + 1;
  int* rp1  = I + q; q += N + 1;
  int* rp2  = I + q; q += S + 1;
  int* rp3  = I + q; q += S + 1;
  int* rp4  = I + q; q += S + 1;
  int* src1s = I + q; q += E;
  int* bs1  = I + q; q += 256;
  int* bs2  = I + q; q += 256;
  int* bs3  = I + q; q += 256;
  int* bs4  = I + q; q += 256;

  u16* WT_c1l  = WTS;
  u16* WT_c1r  = WTS + 12288;
  u16* WT_c2l  = WTS + 24576;
  u16* WT_c2r  = WTS + 36864;
  u16* WT_node = WTS + 49152;
  u16* WT_c3l  = WTS + 51200;
  u16* WT_c3r  = WTS + 79872;
  u16* WT_lin1 = WTS + 108544;
  u16* WT_lin2 = WTS + 137216;

  const int* edst = edge_index + E;

  dim3 blk(256);
  const int gN64 = (N + 63) / 64;
  const int gS64 = (S + 63) / 64;
  const int gS4  = (S + 3) / 4;
  const int gN4  = (N + 3) / 4;
  const int gXF  = (2 * S + 3) / 4;
  const int nbN  = (N + 1 + 1023) / 1024;
  const int nbS  = (S + 1 + 1023) / 1024;

  // ---- fused prep: zero counters + weight transpose/bf16 + NE convert ----
  long ztot = (long)(N + 1) + 3L * (S + 1);
  prep_misc<<<2048, blk, 0, stream>>>(cur1, ztot,
                                      c1_Wl, c1_Wr, c2_Wl, c2_Wr,
                                      node_lin_W, c3_Wl, c3_Wr, lin1_W, lin2_W, WTS,
                                      node_embed, NE, (long)N * 64);
  hist4_k<<<2048, blk, 0, stream>>>(edst, se_row, sn_row, ss_col, E, NNZSS,
                                    cur1, cur2, cur3, cur4);
  scan_p1f<<<nbN + 3 * nbS, blk, 0, stream>>>(cur1, cur2, cur3, cur4,
                                              N + 1, S + 1, nbN, nbS,
                                              bs1, bs2, bs3, bs4);
  scan_p2f<<<4, blk, 0, stream>>>(bs1, bs2, bs3, bs4, nbN, nbS,
                                  rp1, rp2, rp3, rp4, N, S);
  scan_p3f<<<nbN + 3 * nbS, blk, 0, stream>>>(cur1, cur2, cur3, cur4,
                                              N, S, nbN, nbS,
                                              bs1, bs2, bs3, bs4,
                                              rp1, rp2, rp3, rp4,
                                              cur1, cur2, cur3, cur4);
  scat4_k<<<8192, blk, 0, stream>>>(edst, edge_index, attr,
                                    se_row, se_col, se_val,
                                    sn_row, sn_col, sn_val,
                                    ss_col, ss_row, ss_val,
                                    E, NNZSS, N, S,
                                    cur1, cur2, cur3, cur4,
                                    src1s, ATRS, cv2, cv3, cv4);

  compose_we<<<6, blk, 0, stream>>>((const float*)d_in[12], (const float*)d_in[13],
                                    (const float*)d_in[20], (const float*)d_in[27], WECP, BEC);

  // nf0 = gelu(x_rec @ node_lin_W + b), K=32, bf16 out
  gemm_mfma<1, false, false, true, false, false><<<gN64, blk, 0, stream>>>(x_rec, N, 32,
      WT_node, node_lin_b, F0, nullptr, nullptr, nullptr,
      nullptr, nullptr, nullptr, nullptr, nullptr, nullptr, nullptr,
      nullptr, nullptr, nullptr);

  // fused conv1+conv2 stacks: one DUAL pair-GEMM + one gather per layer
  for (int l = 0; l < 3; ++l) {
    gemm_mfma<0, true, true, true, true, false><<<2 * gN64, blk, 0, stream>>>(
        l == 0 ? NE : Hc, N, 64,
        WT_c1l + l * 4096, c1_bl + l * 64, A, WT_c1r + l * 4096, c1_br + l * 64, B,
        l == 0 ? F0 : Fc,
        WT_c2l + l * 4096, c2_bl + l * 64, A2, WT_c2r + l * 4096, c2_br + l * 64, B2,
        nullptr, nullptr, nullptr);
    gat_gather2<<<gN4, blk, 0, stream>>>(rp1, src1s, ATRS,
        WECP + l * 512, BEC + l * 64, c1_att + l * 64, c1_bias + l * 64,
        WECP + (3 + l) * 512, BEC + (3 + l) * 64, c2_att + l * 64, c2_bias + l * 64,
        A, B, NE, Hc,
        A2, B2, F0, Fc, N);
  }

  // xf assembly (role-split: se-wave / sn-wave, 2x edge unroll)
  xf_build<<<gXF, blk, 0, stream>>>(rp2, cv2, rp3, cv3,
                                    edge_embed, attr, attr2_W, attr2_b,
                                    seg_embed, time_embed, week_embed, cur_t, cur_w,
                                    Hc, Fc, XF, S);

  // conv3 pair + lin1 fused (TRI): one pass over XF (K=448)
  gemm_mfma<0, true, false, true, false, true><<<gS64, blk, 0, stream>>>(XF, S, 448,
      WT_c3l, c3_bl, A, WT_c3r, c3_br, B,
      nullptr, nullptr, nullptr, nullptr, nullptr, nullptr, nullptr,
      WT_lin1, lin1_b, Y);
  gat_seg_g<<<gS4, blk, 0, stream>>>(rp4, cv4, c3_We, c3_att, c3_bias,
                                     A, B, XFG, S);

  // lin2 + head
  gemm_mfma<1, false, false, false, false, false><<<gS64, blk, 0, stream>>>(Y, S, 64,
      WT_lin2, lin2_b, Y2, nullptr, nullptr, nullptr,
      nullptr, nullptr, nullptr, nullptr, nullptr, nullptr, nullptr,
      nullptr, nullptr, nullptr);
  head_k<<<gS4, blk, 0, stream>>>(Y2, XFG, out_W, out_b, (float*)d_out, S);
}

// Round 17
// 601.035 us; speedup vs baseline: 1.0172x; 1.0172x over previous
//
#include <hip/hip_runtime.h>
#include <hip/hip_bf16.h>
#include <math.h>

#define DEV __device__ __forceinline__
typedef unsigned short u16;
typedef unsigned int u32;
typedef __attribute__((ext_vector_type(8))) short bf16x8;
typedef __attribute__((ext_vector_type(4))) float f32x4;
typedef __attribute__((ext_vector_type(2))) __bf16 bf16x2;

DEV float gelu_f(float x) { return 0.5f * x * (1.f + erff(x * 0.70710678118654752f)); }
DEV int rfl(int v) { return __builtin_amdgcn_readfirstlane(v); }
DEV float rflf(float v) {
  int i = __builtin_amdgcn_readfirstlane(__float_as_int(v));
  return __int_as_float(i);
}
DEV u16 f2b(float x) { __hip_bfloat16 h = __float2bfloat16(x); return *reinterpret_cast<u16*>(&h); }
DEV float b2f(u16 u) { __hip_bfloat16 h; *reinterpret_cast<u16*>(&h) = u; return __bfloat162float(h); }
DEV u32 pack2(float a, float b) { return (u32)f2b(a) | ((u32)f2b(b) << 16); }

// packed bf16-pair dot with f32 accumulate
DEV float dot2bf(u32 a, u32 b, float c) {
#if __has_builtin(__builtin_amdgcn_fdot2_f32_bf16)
  return __builtin_amdgcn_fdot2_f32_bf16(__builtin_bit_cast(bf16x2, a),
                                         __builtin_bit_cast(bf16x2, b), c, false);
#else
  float r;
  asm("v_dot2_f32_bf16 %0, %1, %2, %3" : "=v"(r) : "v"(a), "v"(b), "v"(c));
  return r;
#endif
}

// ---------------- fused prep: zero counters | weight transpose+bf16 | NE convert ------
__global__ void prep_misc(
    int* __restrict__ zbase, long ztot,
    const float* __restrict__ c1Wl, const float* __restrict__ c1Wr,
    const float* __restrict__ c2Wl, const float* __restrict__ c2Wr,
    const float* __restrict__ nodeW, const float* __restrict__ c3Wl,
    const float* __restrict__ c3Wr, const float* __restrict__ lin1W,
    const float* __restrict__ lin2W, u16* __restrict__ WTS,
    const float* __restrict__ node_embed, u16* __restrict__ NE, long nNE)
{
  long total = ztot + 141312 + nNE;
  long i = (long)blockIdx.x * blockDim.x + threadIdx.x;
  long st = (long)gridDim.x * blockDim.x;
  for (; i < total; i += st) {
    if (i < ztot) {
      zbase[i] = 0;
    } else if (i < ztot + 141312) {
      long idx = i - ztot;
      float v;
      if (idx < 49152) {
        const float* src = (idx < 12288) ? c1Wl : (idx < 24576) ? c1Wr : (idx < 36864) ? c2Wl : c2Wr;
        long loc = idx & 12287;
        long m = loc >> 12;
        int c = (int)((loc >> 6) & 63), k = (int)(loc & 63);
        v = src[m * 4096 + k * 64 + c];
      } else if (idx < 51200) {
        long loc = idx - 49152;
        int c = (int)(loc >> 5), k = (int)(loc & 31);
        v = nodeW[k * 64 + c];
      } else if (idx < 137216) {
        long base = (idx < 79872) ? 51200 : (idx < 108544) ? 79872 : 108544;
        const float* src = (idx < 79872) ? c3Wl : (idx < 108544) ? c3Wr : lin1W;
        long loc = idx - base;
        int c = (int)(loc / 448), k = (int)(loc % 448);
        v = src[k * 64 + c];
      } else {
        long loc = idx - 137216;
        int c = (int)(loc >> 6), k = (int)(loc & 63);
        v = lin2W[k * 64 + c];
      }
      WTS[idx] = f2b(v);
    } else {
      long j = i - ztot - 141312;
      NE[j] = f2b(node_embed[j]);
    }
  }
}

// ---------------- fused histogram over 4 graphs ----------------
__global__ void hist4_k(const int* __restrict__ k1, const int* __restrict__ k2,
                        const int* __restrict__ k3, const int* __restrict__ k4,
                        int E, int Z,
                        int* __restrict__ c1, int* __restrict__ c2,
                        int* __restrict__ c3, int* __restrict__ c4) {
  long total = 3L * E + Z;
  long i = (long)blockIdx.x * blockDim.x + threadIdx.x;
  long st = (long)gridDim.x * blockDim.x;
  for (; i < total; i += st) {
    if (i < E)               atomicAdd(&c1[k1[i]], 1);
    else if (i < 2L * E)     atomicAdd(&c2[k2[i - E]], 1);
    else if (i < 3L * E)     atomicAdd(&c3[k3[i - 2L * E]], 1);
    else                     atomicAdd(&c4[k4[i - 3L * E]], 1);
  }
}

// ---------------- fused multi-block exclusive scan (4 graphs) ----------------
__global__ __launch_bounds__(256) void scan_p1f(
    const int* __restrict__ c1, const int* __restrict__ c2,
    const int* __restrict__ c3, const int* __restrict__ c4,
    int n1, int nS, int nb1, int nbS,
    int* __restrict__ b1, int* __restrict__ b2,
    int* __restrict__ b3, int* __restrict__ b4) {
  int blk = blockIdx.x;
  const int* cnt; int* bsum; int n; int lb;
  if (blk < nb1)                { cnt = c1; bsum = b1; n = n1; lb = blk; }
  else if (blk < nb1 + nbS)     { cnt = c2; bsum = b2; n = nS; lb = blk - nb1; }
  else if (blk < nb1 + 2 * nbS) { cnt = c3; bsum = b3; n = nS; lb = blk - nb1 - nbS; }
  else                          { cnt = c4; bsum = b4; n = nS; lb = blk - nb1 - 2 * nbS; }
  __shared__ int ts[256];
  int base = lb * 1024;
  int s = 0;
  #pragma unroll
  for (int k = 0; k < 4; ++k) {
    int g = base + threadIdx.x * 4 + k;
    if (g < n) s += cnt[g];
  }
  ts[threadIdx.x] = s;
  __syncthreads();
  for (int d = 128; d; d >>= 1) {
    if (threadIdx.x < d) ts[threadIdx.x] += ts[threadIdx.x + d];
    __syncthreads();
  }
  if (threadIdx.x == 0) bsum[lb] = ts[0];
}

__global__ __launch_bounds__(256) void scan_p2f(
    int* __restrict__ b1, int* __restrict__ b2, int* __restrict__ b3, int* __restrict__ b4,
    int nb1, int nbS,
    int* __restrict__ rp1, int* __restrict__ rp2, int* __restrict__ rp3, int* __restrict__ rp4,
    int n1, int nS) {
  int g = blockIdx.x;
  int* bsum = g == 0 ? b1 : g == 1 ? b2 : g == 2 ? b3 : b4;
  int* rp   = g == 0 ? rp1 : g == 1 ? rp2 : g == 2 ? rp3 : rp4;
  int nb    = g == 0 ? nb1 : nbS;
  int n     = g == 0 ? n1 : nS;
  __shared__ int ts[256];
  int tid = threadIdx.x;
  int v = (tid < nb) ? bsum[tid] : 0;
  ts[tid] = v;
  __syncthreads();
  for (int d = 1; d < 256; d <<= 1) {
    int w = (tid >= d) ? ts[tid - d] : 0;
    __syncthreads();
    ts[tid] += w;
    __syncthreads();
  }
  if (tid < nb) bsum[tid] = (tid == 0) ? 0 : ts[tid - 1];
  if (tid == 255) rp[n] = ts[255];
}

__global__ __launch_bounds__(256) void scan_p3f(
    const int* __restrict__ c1, const int* __restrict__ c2,
    const int* __restrict__ c3, const int* __restrict__ c4,
    int n1, int nS, int nb1, int nbS,
    const int* __restrict__ b1, const int* __restrict__ b2,
    const int* __restrict__ b3, const int* __restrict__ b4,
    int* __restrict__ rp1, int* __restrict__ rp2,
    int* __restrict__ rp3, int* __restrict__ rp4,
    int* __restrict__ q1, int* __restrict__ q2,
    int* __restrict__ q3, int* __restrict__ q4) {
  int blk = blockIdx.x;
  const int* cnt; const int* bsum; int* rp; int* cursor; int n; int lb;
  if (blk < nb1)                { cnt = c1; bsum = b1; rp = rp1; cursor = q1; n = n1; lb = blk; }
  else if (blk < nb1 + nbS)     { cnt = c2; bsum = b2; rp = rp2; cursor = q2; n = nS; lb = blk - nb1; }
  else if (blk < nb1 + 2 * nbS) { cnt = c3; bsum = b3; rp = rp3; cursor = q3; n = nS; lb = blk - nb1 - nbS; }
  else                          { cnt = c4; bsum = b4; rp = rp4; cursor = q4; n = nS; lb = blk - nb1 - 2 * nbS; }
  __shared__ int ts[256];
  int base = lb * 1024;
  int tid = threadIdx.x;
  int c[4];
  int s = 0;
  #pragma unroll
  for (int k = 0; k < 4; ++k) {
    int g = base + tid * 4 + k;
    c[k] = (g < n) ? cnt[g] : 0;
    s += c[k];
  }
  ts[tid] = s;
  __syncthreads();
  for (int d = 1; d < 256; d <<= 1) {
    int w = (tid >= d) ? ts[tid - d] : 0;
    __syncthreads();
    ts[tid] += w;
    __syncthreads();
  }
  int run = bsum[lb] + ((tid == 0) ? 0 : ts[tid - 1]);
  #pragma unroll
  for (int k = 0; k < 4; ++k) {
    int g = base + tid * 4 + k;
    if (g < n) {
      rp[g] = run;
      cursor[g] = run;
      run += c[k];
    }
  }
}

// ---------------- partitioned fused scatter: block handles keys in its 1/8 dst range ----
#define NPART 8
__global__ void scat4_k(
    const int* __restrict__ edst, const int* __restrict__ esrc,
    const float* __restrict__ attr,
    const int* __restrict__ se_row, const int* __restrict__ se_col, const float* __restrict__ se_val,
    const int* __restrict__ sn_row, const int* __restrict__ sn_col, const float* __restrict__ sn_val,
    const int* __restrict__ ss_col, const int* __restrict__ ss_row, const float* __restrict__ ss_val,
    int E, int Z, int Nn, int S,
    int* __restrict__ q1, int* __restrict__ q2, int* __restrict__ q3, int* __restrict__ q4,
    int* __restrict__ src1s, u16* __restrict__ atrs,
    int2* __restrict__ cv2, int2* __restrict__ cv3, int2* __restrict__ cv4) {
  const int part = blockIdx.x & (NPART - 1);
  const int nb   = gridDim.x >> 3;
  const int bid  = blockIdx.x >> 3;
  const int nlo = (int)((long)part * Nn / NPART);
  const int nhi = (int)((long)(part + 1) * Nn / NPART);
  const int slo = (int)((long)part * S / NPART);
  const int shi = (int)((long)(part + 1) * S / NPART);
  long total = 3L * E + Z;
  long i = (long)bid * blockDim.x + threadIdx.x;
  long st = (long)nb * blockDim.x;
  for (; i < total; i += st) {
    if (i < E) {
      int key = edst[i];
      if (key < nlo || key >= nhi) continue;
      int p = atomicAdd(&q1[key], 1);
      src1s[p] = esrc[i];
      const float* sr = attr + (size_t)i * 16;
      u32* dr = (u32*)(atrs + (size_t)p * 16);
      #pragma unroll
      for (int k = 0; k < 8; ++k) dr[k] = pack2(sr[2 * k], sr[2 * k + 1]);
    } else if (i < 2L * E) {
      long j = i - E;
      int key = se_row[j];
      if (key < slo || key >= shi) continue;
      int p = atomicAdd(&q2[key], 1);
      cv2[p] = make_int2(se_col[j], __float_as_int(se_val[j]));
    } else if (i < 3L * E) {
      long j = i - 2L * E;
      int key = sn_row[j];
      if (key < slo || key >= shi) continue;
      int p = atomicAdd(&q3[key], 1);
      cv3[p] = make_int2(sn_col[j], __float_as_int(sn_val[j]));
    } else {
      long j = i - 3L * E;
      int key = ss_col[j];
      if (key < slo || key >= shi) continue;
      int p = atomicAdd(&q4[key], 1);
      cv4[p] = make_int2(ss_row[j], __float_as_int(ss_val[j]));
    }
  }
}

// ---------------- compose: WECP = pack_bf16(attr1_W @ We[l]), BEC = attr1_b @ We[l] ------
__global__ __launch_bounds__(256) void compose_we(
    const float* __restrict__ a1W, const float* __restrict__ a1b,
    const float* __restrict__ c1We, const float* __restrict__ c2We,
    u32* __restrict__ WECP, float* __restrict__ BEC)
{
  int l = blockIdx.x;
  const float* We = (l < 3) ? (c1We + l * 4096) : (c2We + (l - 3) * 4096);
  __shared__ float wes[4096];
  __shared__ float wecl[1024];
  int tid = threadIdx.x;
  for (int i = tid; i < 4096; i += 256) wes[i] = We[i];
  __syncthreads();
  for (int i = tid; i < 1024; i += 256) {
    int k = i >> 6, j = i & 63;
    float s = 0.f;
    #pragma unroll 16
    for (int m = 0; m < 64; ++m) s += a1W[k * 64 + m] * wes[m * 64 + j];
    wecl[i] = s;
  }
  if (tid < 64) {
    float s = 0.f;
    for (int m = 0; m < 64; ++m) s += a1b[m] * wes[m * 64 + tid];
    BEC[l * 64 + tid] = s;
  }
  __syncthreads();
  for (int i = tid; i < 512; i += 256) {
    int k = i >> 6, j = i & 63;
    WECP[l * 512 + i] = pack2(wecl[(2 * k) * 64 + j], wecl[(2 * k + 1) * 64 + j]);
  }
}

// ---------------- MFMA GEMM; DUAL: split grid; TRI: third weight set (fp32+gelu out) ----
template <int ACT, bool PAIR, bool XBF, bool OBF, bool DUAL, bool TRI>
__global__ __launch_bounds__(256) void gemm_mfma(
    const void* __restrict__ Xv, int nrows, int K,
    const u16* __restrict__ WT1, const float* __restrict__ b1, void* __restrict__ O1v,
    const u16* __restrict__ WT2, const float* __restrict__ b2, void* __restrict__ O2v,
    const void* __restrict__ Xv2,
    const u16* __restrict__ WT3, const float* __restrict__ b3, void* __restrict__ O3v,
    const u16* __restrict__ WT4, const float* __restrict__ b4, void* __restrict__ O4v,
    const u16* __restrict__ WT5, const float* __restrict__ b5, float* __restrict__ O5v)
{
  __shared__ __align__(16) u16 xs[4096];
  __shared__ __align__(16) u16 ws1[4096];
  __shared__ __align__(16) u16 ws2[PAIR ? 4096 : 8];
  __shared__ __align__(16) u16 ws3[TRI ? 4096 : 8];

  int bid = blockIdx.x;
  const void* X_ = Xv;
  const u16* w1p = WT1; const float* b1p = b1; void* o1p = O1v;
  const u16* w2p = WT2; const float* b2p = b2; void* o2p = O2v;
  if constexpr (DUAL) {
    int half = gridDim.x >> 1;
    if (bid >= half) {
      bid -= half;
      X_ = Xv2;
      w1p = WT3; b1p = b3; o1p = O3v;
      w2p = WT4; b2p = b4; o2p = O4v;
    }
  }

  const int tid = threadIdx.x;
  const int row0 = bid * 64;
  const int wid = tid >> 6, lane = tid & 63;
  const int lrow = lane & 15, lgrp = lane >> 4;
  const int r0 = wid * 16;
  const int sr = tid >> 2;
  const int sq = tid & 3;
  const int ssw = sr & 7;

  f32x4 acc[4];
  f32x4 acc2[PAIR ? 4 : 1];
  f32x4 acc3[TRI ? 4 : 1];
  #pragma unroll
  for (int f = 0; f < 4; ++f) {
    acc[f] = (f32x4)0.f;
    if constexpr (PAIR) acc2[f] = (f32x4)0.f;
    if constexpr (TRI)  acc3[f] = (f32x4)0.f;
  }

  for (int kc = 0; kc < K; kc += 64) {
    __syncthreads();
    {
      int gr = row0 + sr;
      int kb = kc + sq * 16;
      uint4 pa, pb;
      if constexpr (XBF) {
        const u16* X = (const u16*)X_;
        if (gr < nrows && kb + 16 <= K) {
          pa = *(const uint4*)&X[(size_t)gr * K + kb];
          pb = *(const uint4*)&X[(size_t)gr * K + kb + 8];
        } else {
          u32 p[8];
          #pragma unroll
          for (int i = 0; i < 8; ++i) {
            u16 a = (gr < nrows && kb + 2 * i < K)     ? X[(size_t)gr * K + kb + 2 * i]     : (u16)0;
            u16 b = (gr < nrows && kb + 2 * i + 1 < K) ? X[(size_t)gr * K + kb + 2 * i + 1] : (u16)0;
            p[i] = (u32)a | ((u32)b << 16);
          }
          pa = make_uint4(p[0], p[1], p[2], p[3]);
          pb = make_uint4(p[4], p[5], p[6], p[7]);
        }
      } else {
        const float* X = (const float*)X_;
        float f[16];
        if (gr < nrows && kb + 16 <= K) {
          #pragma unroll
          for (int i = 0; i < 4; ++i)
            *(float4*)&f[i * 4] = *(const float4*)&X[(size_t)gr * K + kb + i * 4];
        } else {
          #pragma unroll
          for (int i = 0; i < 16; ++i)
            f[i] = (gr < nrows && kb + i < K) ? X[(size_t)gr * K + kb + i] : 0.f;
        }
        u32 p[8];
        #pragma unroll
        for (int i = 0; i < 8; ++i) p[i] = pack2(f[2 * i], f[2 * i + 1]);
        pa = make_uint4(p[0], p[1], p[2], p[3]);
        pb = make_uint4(p[4], p[5], p[6], p[7]);
      }
      *(uint4*)&xs[sr * 64 + (((sq * 2))     ^ ssw) * 8] = pa;
      *(uint4*)&xs[sr * 64 + (((sq * 2 + 1)) ^ ssw) * 8] = pb;
    }
    {
      int kb = kc + sq * 16;
      uint4 qa, qb;
      #define STAGE_W(WP, WS)                                                       \
        if (kb + 16 <= K) {                                                         \
          qa = *(const uint4*)&WP[(size_t)sr * K + kb];                             \
          qb = *(const uint4*)&WP[(size_t)sr * K + kb + 8];                         \
        } else {                                                                    \
          u32 p[8];                                                                 \
          _Pragma("unroll")                                                         \
          for (int i = 0; i < 8; ++i) {                                             \
            u16 a = (kb + 2 * i < K)     ? WP[(size_t)sr * K + kb + 2 * i]     : (u16)0; \
            u16 b = (kb + 2 * i + 1 < K) ? WP[(size_t)sr * K + kb + 2 * i + 1] : (u16)0; \
            p[i] = (u32)a | ((u32)b << 16);                                         \
          }                                                                         \
          qa = make_uint4(p[0], p[1], p[2], p[3]);                                  \
          qb = make_uint4(p[4], p[5], p[6], p[7]);                                  \
        }                                                                           \
        *(uint4*)&WS[sr * 64 + (((sq * 2))     ^ ssw) * 8] = qa;                    \
        *(uint4*)&WS[sr * 64 + (((sq * 2 + 1)) ^ ssw) * 8] = qb;
      STAGE_W(w1p, ws1)
      if constexpr (PAIR) { STAGE_W(w2p, ws2) }
      if constexpr (TRI)  { STAGE_W(WT5, ws3) }
      #undef STAGE_W
    }
    __syncthreads();
    #pragma unroll
    for (int kh = 0; kh < 2; ++kh) {
      const int g = (4 * kh + lgrp) ^ (lrow & 7);
      bf16x8 a = *(const bf16x8*)&xs[(r0 + lrow) * 64 + g * 8];
      #pragma unroll
      for (int f = 0; f < 4; ++f) {
        int col = f * 16 + lrow;
        bf16x8 b = *(const bf16x8*)&ws1[col * 64 + g * 8];
        acc[f] = __builtin_amdgcn_mfma_f32_16x16x32_bf16(a, b, acc[f], 0, 0, 0);
        if constexpr (PAIR) {
          bf16x8 b2v = *(const bf16x8*)&ws2[col * 64 + g * 8];
          acc2[f] = __builtin_amdgcn_mfma_f32_16x16x32_bf16(a, b2v, acc2[f], 0, 0, 0);
        }
        if constexpr (TRI) {
          bf16x8 b3v = *(const bf16x8*)&ws3[col * 64 + g * 8];
          acc3[f] = __builtin_amdgcn_mfma_f32_16x16x32_bf16(a, b3v, acc3[f], 0, 0, 0);
        }
      }
    }
  }

  #pragma unroll
  for (int f = 0; f < 4; ++f) {
    int col = f * 16 + lrow;
    float bv = b1p[col];
    float bv2 = 0.f, bv3 = 0.f;
    if constexpr (PAIR) bv2 = b2p[col];
    if constexpr (TRI)  bv3 = b5[col];
    #pragma unroll
    for (int r = 0; r < 4; ++r) {
      int grow = row0 + r0 + lgrp * 4 + r;
      if (grow >= nrows) continue;
      float v = acc[f][r] + bv;
      if constexpr (ACT == 1) v = gelu_f(v);
      if constexpr (OBF) ((u16*)o1p)[(size_t)grow * 64 + col] = f2b(v);
      else               ((float*)o1p)[(size_t)grow * 64 + col] = v;
      if constexpr (PAIR) {
        float v2 = acc2[f][r] + bv2;
        if constexpr (ACT == 1) v2 = gelu_f(v2);
        if constexpr (OBF) ((u16*)o2p)[(size_t)grow * 64 + col] = f2b(v2);
        else               ((float*)o2p)[(size_t)grow * 64 + col] = v2;
      }
      if constexpr (TRI) {
        float v3 = gelu_f(acc3[f][r] + bv3);
        O5v[(size_t)grow * 64 + col] = v3;
      }
    }
  }
}

// ---------------- fused dual-conv gather GATv2 (1 dst/wave, 2x edge unroll, dot2 ep) ----
__global__ __launch_bounds__(256) void gat_gather2(
    const int* __restrict__ rowptr,
    const int* __restrict__ srcs, const u16* __restrict__ atrs,
    const u32* __restrict__ wecp1, const float* __restrict__ bec1,
    const float* __restrict__ att1, const float* __restrict__ bias1,
    const u32* __restrict__ wecp2, const float* __restrict__ bec2,
    const float* __restrict__ att2, const float* __restrict__ bias2,
    const u16* __restrict__ xl1, const u16* __restrict__ xr1,
    const u16* __restrict__ pre1, u16* __restrict__ out1,
    const u16* __restrict__ xl2, const u16* __restrict__ xr2,
    const u16* __restrict__ pre2, u16* __restrict__ out2, int n)
{
  int tid = threadIdx.x;
  int wid = tid >> 6, lane = tid & 63;
  int d = blockIdx.x * 4 + wid;
  if (d >= n) return;
  u32 w1p[8], w2p[8];
  #pragma unroll
  for (int k = 0; k < 8; ++k) {
    w1p[k] = wecp1[k * 64 + lane];
    w2p[k] = wecp2[k * 64 + lane];
  }
  float be1 = bec1[lane], be2 = bec2[lane];
  float at1 = att1[lane], at2 = att2[lane];
  float xr1v = b2f(xr1[(size_t)d * 64 + lane]);
  float xr2v = b2f(xr2[(size_t)d * 64 + lane]);
  float n1 = 0.f, d1 = 0.f, n2 = 0.f, d2 = 0.f;
  int j0 = rfl(rowptr[d]), j1 = rfl(rowptr[d + 1]);
  int j = j0;
  for (; j + 2 <= j1; j += 2) {
    int sa = rfl(srcs[j]);
    int sb = rfl(srcs[j + 1]);
    const u32* ara = (const u32*)(atrs + (size_t)j * 16);
    const u32* arb = ara + 8;
    float xl1a = b2f(xl1[(size_t)sa * 64 + lane]);
    float xl2a = b2f(xl2[(size_t)sa * 64 + lane]);
    float xl1b = b2f(xl1[(size_t)sb * 64 + lane]);
    float xl2b = b2f(xl2[(size_t)sb * 64 + lane]);
    float ep1a = be1, ep2a = be2, ep1b = be1, ep2b = be2;
    #pragma unroll
    for (int k = 0; k < 8; ++k) {
      u32 pa_ = ara[k], pb_ = arb[k];
      ep1a = dot2bf(pa_, w1p[k], ep1a);
      ep2a = dot2bf(pa_, w2p[k], ep2a);
      ep1b = dot2bf(pb_, w1p[k], ep1b);
      ep2b = dot2bf(pb_, w2p[k], ep2b);
    }
    float m1a = xl1a + xr1v + ep1a, m2a = xl2a + xr2v + ep2a;
    float m1b = xl1b + xr1v + ep1b, m2b = xl2b + xr2v + ep2b;
    float l1a = m1a < 0.f ? 0.2f * m1a : m1a;
    float l2a = m2a < 0.f ? 0.2f * m2a : m2a;
    float l1b = m1b < 0.f ? 0.2f * m1b : m1b;
    float l2b = m2b < 0.f ? 0.2f * m2b : m2b;
    float t1a = at1 * l1a, t2a = at2 * l2a, t1b = at1 * l1b, t2b = at2 * l2b;
    #pragma unroll
    for (int o = 32; o; o >>= 1) {
      t1a += __shfl_xor(t1a, o, 64);
      t2a += __shfl_xor(t2a, o, 64);
      t1b += __shfl_xor(t1b, o, 64);
      t2b += __shfl_xor(t2b, o, 64);
    }
    float x1a = __expf(t1a), x2a = __expf(t2a), x1b = __expf(t1b), x2b = __expf(t2b);
    n1 += x1a * xl1a + x1b * xl1b; d1 += x1a + x1b;
    n2 += x2a * xl2a + x2b * xl2b; d2 += x2a + x2b;
  }
  for (; j < j1; ++j) {
    int s = rfl(srcs[j]);
    const u32* arow = (const u32*)(atrs + (size_t)j * 16);
    float xl1v = b2f(xl1[(size_t)s * 64 + lane]);
    float xl2v = b2f(xl2[(size_t)s * 64 + lane]);
    float ep1 = be1, ep2 = be2;
    #pragma unroll
    for (int k = 0; k < 8; ++k) {
      u32 pk = arow[k];
      ep1 = dot2bf(pk, w1p[k], ep1);
      ep2 = dot2bf(pk, w2p[k], ep2);
    }
    float m1 = xl1v + xr1v + ep1;
    float m2 = xl2v + xr2v + ep2;
    float lr1 = m1 < 0.f ? 0.2f * m1 : m1;
    float lr2 = m2 < 0.f ? 0.2f * m2 : m2;
    float t1 = at1 * lr1, t2 = at2 * lr2;
    #pragma unroll
    for (int o = 32; o; o >>= 1) {
      t1 += __shfl_xor(t1, o, 64);
      t2 += __shfl_xor(t2, o, 64);
    }
    float ex1 = __expf(t1), ex2 = __expf(t2);
    n1 += ex1 * xl1v; d1 += ex1;
    n2 += ex2 * xl2v; d2 += ex2;
  }
  size_t base = (size_t)d * 64 + lane;
  float v1 = n1 / (d1 + 1e-16f) + bias1[lane];
  float v2 = n2 / (d2 + 1e-16f) + bias2[lane];
  out1[base] = f2b(gelu_f(v1) + b2f(pre1[base]));
  out2[base] = f2b(gelu_f(v2) + b2f(pre2[base]));
}

// ---------------- fused gather GATv2 (segment graph, 1 seg/wave, packed cv) ----------
__global__ __launch_bounds__(256) void gat_seg_g(
    const int* __restrict__ rowptr, const int2* __restrict__ cv,
    const float* __restrict__ we3, const float* __restrict__ att,
    const float* __restrict__ bias,
    const u16* __restrict__ xl, const u16* __restrict__ xr,
    float* __restrict__ out, int n)
{
  int tid = threadIdx.x;
  int wid = tid >> 6, lane = tid & 63;
  int d = blockIdx.x * 4 + wid;
  if (d >= n) return;
  float we3v = we3[lane], attv = att[lane], bsv = bias[lane];
  float xrv = b2f(xr[(size_t)d * 64 + lane]);
  float accn = 0.f, accd = 0.f;
  int j0 = rfl(rowptr[d]), j1 = rfl(rowptr[d + 1]);
  for (int j = j0; j < j1; ++j) {
    int2 r = cv[j];
    int s = rfl(r.x);
    float vv = rflf(__int_as_float(r.y));
    float ep = vv * we3v;
    float xlv = b2f(xl[(size_t)s * 64 + lane]);
    float m = xlv + xrv + ep;
    float lr = m < 0.f ? 0.2f * m : m;
    float t = attv * lr;
    #pragma unroll
    for (int o = 32; o; o >>= 1) t += __shfl_xor(t, o, 64);
    float ex = __expf(t);
    accn += ex * xlv;
    accd += ex;
  }
  float v = accn / (accd + 1e-16f) + bsv;
  out[(size_t)d * 64 + lane] = gelu_f(v);
}

// ---------------- fused xf build, role-split, 2x edge unroll for MLP ----------------
__global__ __launch_bounds__(256) void xf_build(
    const int* __restrict__ rp2, const int2* __restrict__ cv2,
    const int* __restrict__ rp3, const int2* __restrict__ cv3,
    const float* __restrict__ edge_embed, const float* __restrict__ attr,
    const float* __restrict__ W2, const float* __restrict__ b2,
    const float* __restrict__ seg_embed, const float* __restrict__ time_embed,
    const float* __restrict__ week_embed,
    const int* __restrict__ cur_t, const int* __restrict__ cur_w,
    const u16* __restrict__ h, const u16* __restrict__ nf,
    float* __restrict__ xf, int S)
{
  __shared__ float ws[1024];
  __shared__ float bs[64];
  int tid = threadIdx.x;
  for (int i = tid; i < 1024; i += 256) ws[i] = W2[i];
  if (tid < 64) bs[tid] = b2[tid];
  __syncthreads();
  int wid = tid >> 6, lane = tid & 63;
  int gw = blockIdx.x * 4 + wid;
  int s = gw >> 1, role = gw & 1;
  if (s >= S) return;
  float* row = xf + (size_t)s * 448;
  if (role == 0) {
    row[lane]       = seg_embed[(size_t)s * 64 + lane];
    row[320 + lane] = time_embed[cur_t[0] * 64 + lane];
    row[384 + lane] = week_embed[cur_w[0] * 64 + lane];
    float acc1 = 0.f, aat = 0.f, vs = 0.f;
    int j0 = rfl(rp2[s]), j1 = rfl(rp2[s + 1]);
    int j = j0;
    for (; j + 2 <= j1; j += 2) {
      int2 ra = cv2[j], rb = cv2[j + 1];
      int ca = rfl(ra.x), cb = rfl(rb.x);
      float va = rflf(__int_as_float(ra.y)), vb = rflf(__int_as_float(rb.y));
      float ea = edge_embed[(size_t)ca * 64 + lane];
      float eb = edge_embed[(size_t)cb * 64 + lane];
      float aa = attr[(size_t)ca * 16 + (lane & 15)];
      float ab = attr[(size_t)cb * 16 + (lane & 15)];
      acc1 += va * ea + vb * eb;
      aat  += va * aa + vb * ab;
      vs   += va + vb;
    }
    for (; j < j1; ++j) {
      int2 r = cv2[j];
      int c = rfl(r.x);
      float v = rflf(__int_as_float(r.y));
      acc1 += v * edge_embed[(size_t)c * 64 + lane];
      aat  += v * attr[(size_t)c * 16 + (lane & 15)];
      vs   += v;
    }
    float x2 = vs * bs[lane];
    #pragma unroll
    for (int k = 0; k < 16; ++k)
      x2 += __shfl(aat, k, 64) * ws[k * 64 + lane];
    row[64 + lane]  = acc1;
    row[128 + lane] = x2;
  } else {
    float acch = 0.f, accf = 0.f;
    int j0 = rfl(rp3[s]), j1 = rfl(rp3[s + 1]);
    int j = j0;
    for (; j + 2 <= j1; j += 2) {
      int2 ra = cv3[j], rb = cv3[j + 1];
      int ca = rfl(ra.x), cb = rfl(rb.x);
      float va = rflf(__int_as_float(ra.y)), vb = rflf(__int_as_float(rb.y));
      float ha = b2f(h[(size_t)ca * 64 + lane]);
      float hb = b2f(h[(size_t)cb * 64 + lane]);
      float fa = b2f(nf[(size_t)ca * 64 + lane]);
      float fb = b2f(nf[(size_t)cb * 64 + lane]);
      acch += va * ha + vb * hb;
      accf += va * fa + vb * fb;
    }
    for (; j < j1; ++j) {
      int2 r = cv3[j];
      int c = rfl(r.x);
      float v = rflf(__int_as_float(r.y));
      acch += v * b2f(h[(size_t)c * 64 + lane]);
      accf += v * b2f(nf[(size_t)c * 64 + lane]);
    }
    row[192 + lane] = acch;
    row[256 + lane] = accf;
  }
}

// ---------------- head ----------------
__global__ __launch_bounds__(256) void head_k(
    const float* __restrict__ y2, const float* __restrict__ xfg,
    const float* __restrict__ outW, const float* __restrict__ outb,
    float* __restrict__ out, int S)
{
  int wid = threadIdx.x >> 6, lane = threadIdx.x & 63;
  int s = blockIdx.x * 4 + wid;
  if (s >= S) return;
  float t = y2[(size_t)s * 64 + lane] * outW[lane] + xfg[(size_t)s * 64 + lane] * outW[64 + lane];
  #pragma unroll
  for (int o = 32; o; o >>= 1) t += __shfl_xor(t, o, 64);
  if (lane == 0) {
    float z = t + outb[0];
    out[s] = 3600.f / (1.f + __expf(-z));
  }
}

extern "C" void kernel_launch(void* const* d_in, const int* in_sizes, int n_in,
                              void* d_out, int out_size, void* d_ws, size_t ws_size,
                              hipStream_t stream)
{
  const float* x_rec       = (const float*)d_in[0];
  const float* attr        = (const float*)d_in[1];
  const float* se_val      = (const float*)d_in[2];
  const float* sn_val      = (const float*)d_in[3];
  const float* ss_val      = (const float*)d_in[4];
  const float* node_embed  = (const float*)d_in[5];
  const float* edge_embed  = (const float*)d_in[6];
  const float* seg_embed   = (const float*)d_in[7];
  const float* time_embed  = (const float*)d_in[8];
  const float* week_embed  = (const float*)d_in[9];
  const float* node_lin_W  = (const float*)d_in[10];
  const float* node_lin_b  = (const float*)d_in[11];
  const float* attr2_W     = (const float*)d_in[14];
  const float* attr2_b     = (const float*)d_in[15];
  const float* c1_Wl       = (const float*)d_in[16];
  const float* c1_bl       = (const float*)d_in[17];
  const float* c1_Wr       = (const float*)d_in[18];
  const float* c1_br       = (const float*)d_in[19];
  const float* c1_att      = (const float*)d_in[21];
  const float* c1_bias     = (const float*)d_in[22];
  const float* c2_Wl       = (const float*)d_in[23];
  const float* c2_bl       = (const float*)d_in[24];
  const float* c2_Wr       = (const float*)d_in[25];
  const float* c2_br       = (const float*)d_in[26];
  const float* c2_att      = (const float*)d_in[28];
  const float* c2_bias     = (const float*)d_in[29];
  const float* c3_Wl       = (const float*)d_in[30];
  const float* c3_bl       = (const float*)d_in[31];
  const float* c3_Wr       = (const float*)d_in[32];
  const float* c3_br       = (const float*)d_in[33];
  const float* c3_We       = (const float*)d_in[34];
  const float* c3_att      = (const float*)d_in[35];
  const float* c3_bias     = (const float*)d_in[36];
  const float* lin1_W      = (const float*)d_in[37];
  const float* lin1_b      = (const float*)d_in[38];
  const float* lin2_W      = (const float*)d_in[39];
  const float* lin2_b      = (const float*)d_in[40];
  const float* out_W       = (const float*)d_in[41];
  const float* out_b       = (const float*)d_in[42];
  const int* edge_index    = (const int*)d_in[43];
  const int* se_row        = (const int*)d_in[44];
  const int* se_col        = (const int*)d_in[45];
  const int* sn_row        = (const int*)d_in[46];
  const int* sn_col        = (const int*)d_in[47];
  const int* ss_row        = (const int*)d_in[48];
  const int* ss_col        = (const int*)d_in[49];
  const int* cur_t         = (const int*)d_in[50];
  const int* cur_w         = (const int*)d_in[51];

  const int N = in_sizes[0] / 32;
  const int E = in_sizes[1] / 16;
  const int S = in_sizes[7] / 64;
  const int NNZSS = in_sizes[4];

  // workspace layout (float units)
  float* W = (float*)d_ws;
  size_t o = 0;
  u16* A   = (u16*)(W + o); o += (size_t)N * 32;
  u16* B   = (u16*)(W + o); o += (size_t)N * 32;
  u16* A2  = (u16*)(W + o); o += (size_t)N * 32;
  u16* B2  = (u16*)(W + o); o += (size_t)N * 32;
  u16* Hc  = (u16*)(W + o); o += (size_t)N * 32;
  u16* F0  = (u16*)(W + o); o += (size_t)N * 32;
  u16* Fc  = (u16*)(W + o); o += (size_t)N * 32;
  u16* NE  = (u16*)(W + o); o += (size_t)N * 32;  // node_embed bf16
  u16* ATRS = (u16*)(W + o); o += (size_t)E * 8;  // CSR-ordered bf16 attr rows
  float* XF  = W + o; o += (size_t)S * 448;
  float* XFG = W + o; o += (size_t)S * 64;
  float* Y   = W + o; o += (size_t)S * 64;
  float* Y2  = W + o; o += (size_t)S * 64;
  u32* WECP  = (u32*)(W + o); o += 6 * 512;       // packed bf16-pair composed We
  float* BEC = W + o; o += 6 * 64;
  u16* WTS   = (u16*)(W + o); o += 70656;
  int2* cv2  = (int2*)(W + o); o += 2L * E;       // packed (col,val) records
  int2* cv3  = (int2*)(W + o); o += 2L * E;
  int2* cv4  = (int2*)(W + o); o += 2L * NNZSS;
  int* I = (int*)(W + o);
  size_t q = 0;
  int* cur1 = I + q; q += N + 1;
  int* cur2 = I + q; q += S + 1;
  int* cur3 = I + q; q += S + 1;
  int* cur4 = I + q; q += S + 1;
  int* rp1  = I + q; q += N + 1;
  int* rp2  = I + q; q += S + 1;
  int* rp3  = I + q; q += S + 1;
  int* rp4  = I + q; q += S + 1;
  int* src1s = I + q; q += E;
  int* bs1  = I + q; q += 256;
  int* bs2  = I + q; q += 256;
  int* bs3  = I + q; q += 256;
  int* bs4  = I + q; q += 256;

  u16* WT_c1l  = WTS;
  u16* WT_c1r  = WTS + 12288;
  u16* WT_c2l  = WTS + 24576;
  u16* WT_c2r  = WTS + 36864;
  u16* WT_node = WTS + 49152;
  u16* WT_c3l  = WTS + 51200;
  u16* WT_c3r  = WTS + 79872;
  u16* WT_lin1 = WTS + 108544;
  u16* WT_lin2 = WTS + 137216;

  const int* edst = edge_index + E;

  dim3 blk(256);
  const int gN64 = (N + 63) / 64;
  const int gS64 = (S + 63) / 64;
  const int gS4  = (S + 3) / 4;
  const int gN4  = (N + 3) / 4;
  const int gXF  = (2 * S + 3) / 4;
  const int nbN  = (N + 1 + 1023) / 1024;
  const int nbS  = (S + 1 + 1023) / 1024;

  // ---- fused prep: zero counters + weight transpose/bf16 + NE convert ----
  long ztot = (long)(N + 1) + 3L * (S + 1);
  prep_misc<<<2048, blk, 0, stream>>>(cur1, ztot,
                                      c1_Wl, c1_Wr, c2_Wl, c2_Wr,
                                      node_lin_W, c3_Wl, c3_Wr, lin1_W, lin2_W, WTS,
                                      node_embed, NE, (long)N * 64);
  hist4_k<<<2048, blk, 0, stream>>>(edst, se_row, sn_row, ss_col, E, NNZSS,
                                    cur1, cur2, cur3, cur4);
  scan_p1f<<<nbN + 3 * nbS, blk, 0, stream>>>(cur1, cur2, cur3, cur4,
                                              N + 1, S + 1, nbN, nbS,
                                              bs1, bs2, bs3, bs4);
  scan_p2f<<<4, blk, 0, stream>>>(bs1, bs2, bs3, bs4, nbN, nbS,
                                  rp1, rp2, rp3, rp4, N, S);
  scan_p3f<<<nbN + 3 * nbS, blk, 0, stream>>>(cur1, cur2, cur3, cur4,
                                              N, S, nbN, nbS,
                                              bs1, bs2, bs3, bs4,
                                              rp1, rp2, rp3, rp4,
                                              cur1, cur2, cur3, cur4);
  scat4_k<<<8192, blk, 0, stream>>>(edst, edge_index, attr,
                                    se_row, se_col, se_val,
                                    sn_row, sn_col, sn_val,
                                    ss_col, ss_row, ss_val,
                                    E, NNZSS, N, S,
                                    cur1, cur2, cur3, cur4,
                                    src1s, ATRS, cv2, cv3, cv4);

  compose_we<<<6, blk, 0, stream>>>((const float*)d_in[12], (const float*)d_in[13],
                                    (const float*)d_in[20], (const float*)d_in[27], WECP, BEC);

  // nf0 = gelu(x_rec @ node_lin_W + b), K=32, bf16 out
  gemm_mfma<1, false, false, true, false, false><<<gN64, blk, 0, stream>>>(x_rec, N, 32,
      WT_node, node_lin_b, F0, nullptr, nullptr, nullptr,
      nullptr, nullptr, nullptr, nullptr, nullptr, nullptr, nullptr,
      nullptr, nullptr, nullptr);

  // fused conv1+conv2 stacks: one DUAL pair-GEMM + one gather per layer
  for (int l = 0; l < 3; ++l) {
    gemm_mfma<0, true, true, true, true, false><<<2 * gN64, blk, 0, stream>>>(
        l == 0 ? NE : Hc, N, 64,
        WT_c1l + l * 4096, c1_bl + l * 64, A, WT_c1r + l * 4096, c1_br + l * 64, B,
        l == 0 ? F0 : Fc,
        WT_c2l + l * 4096, c2_bl + l * 64, A2, WT_c2r + l * 4096, c2_br + l * 64, B2,
        nullptr, nullptr, nullptr);
    gat_gather2<<<gN4, blk, 0, stream>>>(rp1, src1s, ATRS,
        WECP + l * 512, BEC + l * 64, c1_att + l * 64, c1_bias + l * 64,
        WECP + (3 + l) * 512, BEC + (3 + l) * 64, c2_att + l * 64, c2_bias + l * 64,
        A, B, NE, Hc,
        A2, B2, F0, Fc, N);
  }

  // xf assembly (role-split: se-wave / sn-wave, 2x edge unroll)
  xf_build<<<gXF, blk, 0, stream>>>(rp2, cv2, rp3, cv3,
                                    edge_embed, attr, attr2_W, attr2_b,
                                    seg_embed, time_embed, week_embed, cur_t, cur_w,
                                    Hc, Fc, XF, S);

  // conv3 pair + lin1 fused (TRI): one pass over XF (K=448)
  gemm_mfma<0, true, false, true, false, true><<<gS64, blk, 0, stream>>>(XF, S, 448,
      WT_c3l, c3_bl, A, WT_c3r, c3_br, B,
      nullptr, nullptr, nullptr, nullptr, nullptr, nullptr, nullptr,
      WT_lin1, lin1_b, Y);
  gat_seg_g<<<gS4, blk, 0, stream>>>(rp4, cv4, c3_We, c3_att, c3_bias,
                                     A, B, XFG, S);

  // lin2 + head
  gemm_mfma<1, false, false, false, false, false><<<gS64, blk, 0, stream>>>(Y, S, 64,
      WT_lin2, lin2_b, Y2, nullptr, nullptr, nullptr,
      nullptr, nullptr, nullptr, nullptr, nullptr, nullptr, nullptr,
      nullptr, nullptr, nullptr);
  head_k<<<gS4, blk, 0, stream>>>(Y2, XFG, out_W, out_b, (float*)d_out, S);
}